// Round 7
// baseline (333.918 us; speedup 1.0000x reference)
//
#include <hip/hip_runtime.h>
#include <math.h>

#define NEG_SLOPE 0.2f

typedef __attribute__((ext_vector_type(8))) short bf16x8;
typedef __attribute__((ext_vector_type(4))) float f32x4;
typedef __attribute__((ext_vector_type(4))) unsigned short u16x4;
typedef __attribute__((ext_vector_type(8))) unsigned short u16x8;

static __device__ __forceinline__ f32x4 lky4(f32x4 v) {
    f32x4 r;
    r.x = v.x >= 0.f ? v.x : NEG_SLOPE * v.x;
    r.y = v.y >= 0.f ? v.y : NEG_SLOPE * v.y;
    r.z = v.z >= 0.f ? v.z : NEG_SLOPE * v.z;
    r.w = v.w >= 0.f ? v.w : NEG_SLOPE * v.w;
    return r;
}
static __device__ __forceinline__ f32x4 exp4(f32x4 v) {
    f32x4 r;
    r.x = __expf(v.x); r.y = __expf(v.y); r.z = __expf(v.z); r.w = __expf(v.w);
    return r;
}
static __device__ __forceinline__ float bf2f(unsigned short u) {
    return __uint_as_float(((unsigned int)u) << 16);
}
static __device__ __forceinline__ unsigned short f2bf_rne(float f) {
    unsigned int u = __float_as_uint(f);
    u += 0x7fffu + ((u >> 16) & 1u);
    return (unsigned short)(u >> 16);
}

// ---------------- CSR build ----------------

__global__ void hist_kernel(const int* __restrict__ dst, int* __restrict__ counts, int E, int Nn) {
    int i = blockIdx.x * blockDim.x + threadIdx.x;
    int tot = E + Nn;
    if (i < tot) {
        int d = (i < E) ? dst[i] : (i - E);
        atomicAdd(&counts[d], 1);
    }
}

__global__ void scan1_kernel(const int* __restrict__ counts, int* __restrict__ partial,
                             int* __restrict__ blockSums, int Nn) {
    __shared__ int sh[1024];
    int b = blockIdx.x, t = threadIdx.x;
    int base = b * 1024;
    int orig[4];
    for (int r = 0; r < 4; r++) {
        int i = t + r * 256;
        int v = (base + i < Nn) ? counts[base + i] : 0;
        orig[r] = v;
        sh[i] = v;
    }
    __syncthreads();
    for (int off = 1; off < 1024; off <<= 1) {
        int vals[4];
        for (int r = 0; r < 4; r++) { int i = t + r * 256; vals[r] = (i >= off) ? sh[i - off] : 0; }
        __syncthreads();
        for (int r = 0; r < 4; r++) { int i = t + r * 256; sh[i] += vals[r]; }
        __syncthreads();
    }
    for (int r = 0; r < 4; r++) {
        int i = t + r * 256;
        if (base + i < Nn) partial[base + i] = sh[i] - orig[r];
    }
    if (t == 0) blockSums[b] = sh[1023];
}

__global__ void scan2_kernel(int* __restrict__ blockSums, int nb) {
    if (threadIdx.x == 0 && blockIdx.x == 0) {
        int s = 0;
        for (int i = 0; i < nb; i++) { int v = blockSums[i]; blockSums[i] = s; s += v; }
    }
}

__global__ void finalize_kernel(const int* __restrict__ partial, const int* __restrict__ blockOff,
                                int* __restrict__ row_ptr, int Nn, int Etot) {
    int i = blockIdx.x * blockDim.x + threadIdx.x;
    if (i < Nn) row_ptr[i] = partial[i] + blockOff[i >> 10];
    if (i == 0) row_ptr[Nn] = Etot;
}

__global__ void scatter_kernel(const int* __restrict__ srcE, const int* __restrict__ dstE,
                               const int* __restrict__ row_ptr, int* __restrict__ fill,
                               int* __restrict__ srcs, int E, int Nn) {
    int i = blockIdx.x * blockDim.x + threadIdx.x;
    int tot = E + Nn;
    if (i < tot) {
        int s, d;
        if (i < E) { s = srcE[i]; d = dstE[i]; }
        else       { s = d = i - E; }
        int pos = row_ptr[d] + atomicAdd(&fill[d], 1);
        srcs[pos] = s;
    }
}

// ---------------- fp32 -> bf16 RNE ----------------
__global__ void convertA_kernel(const float* __restrict__ X, unsigned short* __restrict__ Ab,
                                int rows) {
    int t = blockIdx.x * 256 + threadIdx.x;
    if (t >= rows * 64) return;
    int r = t >> 6, c4 = t & 63;
    f32x4 v = *((const f32x4*)(X + ((size_t)r << 8)) + c4);
    u16x4 o;
    o.x = f2bf_rne(v.x); o.y = f2bf_rne(v.y);
    o.z = f2bf_rne(v.z); o.w = f2bf_rne(v.w);
    *(u16x4*)(Ab + (size_t)r * 256 + c4 * 4) = o;
}

// W[k][n] fp32 -> Bt[n][k] bf16 RNE  (Bt: [256][256])
__global__ void transposeW_kernel(const float* __restrict__ W, unsigned short* __restrict__ Bt) {
    int t = blockIdx.x * 256 + threadIdx.x;   // 65536 threads
    int n = t >> 8, k = t & 255;
    Bt[(size_t)n * 256 + k] = f2bf_rne(W[k * 256 + n]);
}

// ---------------- bf16 MFMA GEMM, K=256, 2-phase dbuf, fused attn epilogue --------
// Gb[rows,256] (bf16 RNE) = Ab x Bt^T.
// Each wave (wr,wc) of block (bm, bn) owns cols [bn + wc*64, +64) == exactly one
// head (= blockIdx.y*2 + wc) for its 64 rows -> a_src/a_dst via in-wave reduce +
// plain store (unique (row,head) owner; no atomics).
__global__ __launch_bounds__(256) void gemm_kernel(const unsigned short* __restrict__ Ab,
                                                   const unsigned short* __restrict__ Bt,
                                                   unsigned short* __restrict__ Gb,
                                                   const float* __restrict__ att_s,
                                                   const float* __restrict__ att_d,
                                                   float* __restrict__ a_src,
                                                   float* __restrict__ a_dst,
                                                   int rows) {
    __shared__ __align__(128) unsigned char smem[65536];   // 2 x (As 16KB + Bs 16KB)

    int tid = threadIdx.x;
    int lane = tid & 63, wid = tid >> 6;
    int wr = wid >> 1, wc = wid & 1;
    int bm = blockIdx.x * 128;
    int bn = blockIdx.y * 128;

    f32x4 zero4 = {0.f, 0.f, 0.f, 0.f};
    f32x4 acc[4][4];
#pragma unroll
    for (int i = 0; i < 4; i++)
#pragma unroll
        for (int j = 0; j < 4; j++) acc[i][j] = zero4;

    int sr = tid >> 3;   // 0..31
    int sc = tid & 7;    // chunk 0..7

    auto stage = [&](int kt, int buf) {
        unsigned short* As = (unsigned short*)(smem + buf * 32768);
        unsigned short* Bs = As + 8192;
#pragma unroll
        for (int q = 0; q < 4; q++) {
            int rt = q * 32 + sr;
            int gr = bm + rt; if (gr >= rows) gr = rows - 1;
            int cg = sc ^ (rt & 7);
            const unsigned short* gp = Ab + (size_t)gr * 256 + kt + cg * 8;
            unsigned short* lp = As + rt * 64 + sc * 8;
            __builtin_amdgcn_global_load_lds(
                (__attribute__((address_space(1))) void*)(uintptr_t)gp,
                (__attribute__((address_space(3))) void*)lp, 16, 0, 0);
        }
#pragma unroll
        for (int q = 0; q < 4; q++) {
            int rt = q * 32 + sr;
            int gn = bn + rt;
            int cg = sc ^ (rt & 7);
            const unsigned short* gp = Bt + (size_t)gn * 256 + kt + cg * 8;
            unsigned short* lp = Bs + rt * 64 + sc * 8;
            __builtin_amdgcn_global_load_lds(
                (__attribute__((address_space(1))) void*)(uintptr_t)gp,
                (__attribute__((address_space(3))) void*)lp, 16, 0, 0);
        }
    };

    stage(0, 0);
    __syncthreads();

    for (int kt = 0; kt < 4; kt++) {
        if (kt < 3) stage((kt + 1) * 64, (kt + 1) & 1);
        unsigned short* As = (unsigned short*)(smem + (kt & 1) * 32768);
        unsigned short* Bs = As + 8192;
#pragma unroll
        for (int ks = 0; ks < 2; ks++) {
            bf16x8 af[4], bfr[4];
#pragma unroll
            for (int f = 0; f < 4; f++) {
                int r = wr * 64 + f * 16 + (lane & 15);
                int c = (ks * 4 + (lane >> 4)) ^ (r & 7);
                af[f] = *(const bf16x8*)(As + r * 64 + c * 8);
                int rb = wc * 64 + f * 16 + (lane & 15);
                int cb = (ks * 4 + (lane >> 4)) ^ (rb & 7);
                bfr[f] = *(const bf16x8*)(Bs + rb * 64 + cb * 8);
            }
#pragma unroll
            for (int i = 0; i < 4; i++)
#pragma unroll
                for (int j = 0; j < 4; j++)
                    acc[i][j] = __builtin_amdgcn_mfma_f32_16x16x32_bf16(af[i], bfr[j], acc[i][j], 0, 0, 0);
        }
        __syncthreads();
    }

    // C store (bf16 RNE)
    int r0 = wr * 64 + (lane >> 4) * 4;
    int c0 = wc * 64 + (lane & 15);
#pragma unroll
    for (int i = 0; i < 4; i++) {
#pragma unroll
        for (int j = 0; j < 4; j++) {
#pragma unroll
            for (int rg = 0; rg < 4; rg++) {
                int lr = bm + r0 + i * 16 + rg;
                if (lr < rows) {
                    int col = bn + c0 + j * 16;
                    Gb[(size_t)lr * 256 + col] = f2bf_rne(acc[i][j][rg]);
                }
            }
        }
    }

    // fused attention coefficients from fp32 acc
    int head = blockIdx.y * 2 + wc;
    float atts[4], attd[4];
#pragma unroll
    for (int j = 0; j < 4; j++) {
        int c = bn + c0 + j * 16;      // == head*64 + (c & 63)
        atts[j] = att_s[c];
        attd[j] = att_d[c];
    }
#pragma unroll
    for (int i = 0; i < 4; i++) {
#pragma unroll
        for (int rg = 0; rg < 4; rg++) {
            float s_loc = 0.f, d_loc = 0.f;
#pragma unroll
            for (int j = 0; j < 4; j++) {
                s_loc = fmaf(acc[i][j][rg], atts[j], s_loc);
                d_loc = fmaf(acc[i][j][rg], attd[j], d_loc);
            }
#pragma unroll
            for (int off = 1; off < 16; off <<= 1) {
                s_loc += __shfl_xor(s_loc, off);
                d_loc += __shfl_xor(d_loc, off);
            }
            if ((lane & 15) == 0) {
                int lr = bm + r0 + i * 16 + rg;
                if (lr < rows) {
                    a_src[lr * 4 + head] = s_loc;
                    a_dst[lr * 4 + head] = d_loc;
                }
            }
        }
    }
}

// ---------------- normalized edge weights (wave per node) ----------------
// No max-subtraction: alphas are O(10), exp() safe in fp32; softmax shift-invariant.
__global__ __launch_bounds__(256) void wts_kernel(const float* __restrict__ a_src,
                                                  const float* __restrict__ a_dst,
                                                  const int* __restrict__ row_ptr,
                                                  const int* __restrict__ srcs,
                                                  float* __restrict__ wts, int N) {
    int wv = threadIdx.x >> 6, lane = threadIdx.x & 63;
    int n = blockIdx.x * 4 + wv;
    if (n >= N) return;
    int start = row_ptr[n], end = row_ptr[n + 1];
    const f32x4* as4p = (const f32x4*)a_src;
    f32x4 adn4 = *(const f32x4*)(a_dst + (size_t)n * 4);

    f32x4 zero = {0.f, 0.f, 0.f, 0.f};
    f32x4 ev0 = zero;
    int e0 = start + lane;
    if (e0 < end) {
        int s = srcs[e0];
        ev0 = exp4(lky4(as4p[s] + adn4));
    }
    f32x4 denom4 = ev0;
    for (int c0 = start + 64; c0 < end; c0 += 64) {   // rare (>64-degree nodes)
        int e = c0 + lane;
        if (e < end) {
            int s = srcs[e];
            denom4 += exp4(lky4(as4p[s] + adn4));
        }
    }
#pragma unroll
    for (int off = 32; off; off >>= 1) {
        denom4.x += __shfl_xor(denom4.x, off);
        denom4.y += __shfl_xor(denom4.y, off);
        denom4.z += __shfl_xor(denom4.z, off);
        denom4.w += __shfl_xor(denom4.w, off);
    }
    f32x4 rd;
    rd.x = 1.0f / denom4.x; rd.y = 1.0f / denom4.y;
    rd.z = 1.0f / denom4.z; rd.w = 1.0f / denom4.w;

    if (e0 < end) ((f32x4*)wts)[e0] = ev0 * rd;
    for (int c0 = start + 64; c0 < end; c0 += 64) {
        int e = c0 + lane;
        if (e < end) {
            int s = srcs[e];
            ((f32x4*)wts)[e] = exp4(lky4(as4p[s] + adn4)) * rd;
        }
    }
}

// ---------------- weighted gather (wave per node, LDS-staged indices) ----------------
// Per 64-edge chunk: coalesced batch-load of srcs + wts into wave-private LDS,
// then 4 rows in flight per half-wave with broadcast LDS index/weight reads --
// no serial index->row load dependency chain.
// outF != null -> fp32 (+bias), no relu (final layer)
// outB != null -> relu(h)+bias as bf16 RNE (next layer's GEMM input)
__global__ __launch_bounds__(256) void gather_kernel(const unsigned short* __restrict__ Gb,
                                                     const float* __restrict__ wts,
                                                     const int* __restrict__ row_ptr,
                                                     const int* __restrict__ srcs,
                                                     const float* __restrict__ bias,
                                                     float* __restrict__ outF,
                                                     unsigned short* __restrict__ outB,
                                                     int N) {
    __shared__ int s_lds[4][64];
    __shared__ f32x4 w_lds[4][64];
    int wv = threadIdx.x >> 6, lane = threadIdx.x & 63;
    int n = blockIdx.x * 4 + wv;
    if (n >= N) return;
    int half = lane >> 5;   // which edge of a pair
    int sl = lane & 31;     // 16B slice of the 512B row
    int head = sl >> 3;

    int start = row_ptr[n], end = row_ptr[n + 1];

    float acc[8] = {0.f, 0.f, 0.f, 0.f, 0.f, 0.f, 0.f, 0.f};

    for (int c0 = start; c0 < end; c0 += 64) {
        int cnt = min(64, end - c0);
        if (lane < cnt) {
            s_lds[wv][lane] = srcs[c0 + lane];
            w_lds[wv][lane] = ((const f32x4*)wts)[c0 + lane];
        }
        // wave-private staging; compiler inserts lgkmcnt waits before reads

        int j = 0;
        for (; j + 7 < cnt; j += 8) {
            int e0 = j + half, e1 = j + 2 + half, e2 = j + 4 + half, e3 = j + 6 + half;
            int s0 = s_lds[wv][e0];
            int s1 = s_lds[wv][e1];
            int s2 = s_lds[wv][e2];
            int s3 = s_lds[wv][e3];
            float w0 = ((const float*)&w_lds[wv][e0])[head];
            float w1 = ((const float*)&w_lds[wv][e1])[head];
            float w2 = ((const float*)&w_lds[wv][e2])[head];
            float w3 = ((const float*)&w_lds[wv][e3])[head];
            u16x8 g0 = *(const u16x8*)(Gb + (size_t)s0 * 256 + sl * 8);
            u16x8 g1 = *(const u16x8*)(Gb + (size_t)s1 * 256 + sl * 8);
            u16x8 g2 = *(const u16x8*)(Gb + (size_t)s2 * 256 + sl * 8);
            u16x8 g3 = *(const u16x8*)(Gb + (size_t)s3 * 256 + sl * 8);
#pragma unroll
            for (int k = 0; k < 8; k++) {
                acc[k] = fmaf(bf2f(g0[k]), w0, acc[k]);
                acc[k] = fmaf(bf2f(g1[k]), w1, acc[k]);
                acc[k] = fmaf(bf2f(g2[k]), w2, acc[k]);
                acc[k] = fmaf(bf2f(g3[k]), w3, acc[k]);
            }
        }
        for (; j < cnt; j += 2) {
            int e = j + half;
            if (e < cnt) {
                int s0 = s_lds[wv][e];
                float w0 = ((const float*)&w_lds[wv][e])[head];
                u16x8 g0 = *(const u16x8*)(Gb + (size_t)s0 * 256 + sl * 8);
#pragma unroll
                for (int k = 0; k < 8; k++)
                    acc[k] = fmaf(bf2f(g0[k]), w0, acc[k]);
            }
        }
    }

#pragma unroll
    for (int k = 0; k < 8; k++) acc[k] += __shfl_xor(acc[k], 32);

    float r[8];
    const float* bp = bias + sl * 8;
#pragma unroll
    for (int k = 0; k < 8; k++) r[k] = acc[k] + bp[k];

    if (outF) {
        if (half == 0) {
            f32x4 v0 = {r[0], r[1], r[2], r[3]};
            f32x4 v1 = {r[4], r[5], r[6], r[7]};
            f32x4* op = (f32x4*)(outF + (size_t)n * 256 + sl * 8);
            op[0] = v0; op[1] = v1;
        }
    } else {
        if (half == 0) {
            u16x8 v;
#pragma unroll
            for (int k = 0; k < 8; k++) v[k] = f2bf_rne(fmaxf(r[k], 0.f));
            *(u16x8*)(outB + (size_t)n * 256 + sl * 8) = v;
        }
    }
}

// ---------------- launch ----------------

extern "C" void kernel_launch(void* const* d_in, const int* in_sizes, int n_in,
                              void* d_out, int out_size, void* d_ws, size_t ws_size,
                              hipStream_t stream) {
    const float* x   = (const float*)d_in[0];
    const int*   ei  = (const int*)d_in[1];
    const float* W1  = (const float*)d_in[2];
    const float* as1 = (const float*)d_in[3];
    const float* ad1 = (const float*)d_in[4];
    const float* b1  = (const float*)d_in[5];
    const float* W2  = (const float*)d_in[6];
    const float* as2 = (const float*)d_in[7];
    const float* ad2 = (const float*)d_in[8];
    const float* b2  = (const float*)d_in[9];

    int N = in_sizes[0] / 256;
    int E = in_sizes[1] / 2;
    int Etot = E + N;
    const int* srcE = ei;
    const int* dstE = ei + E;
    float* out = (float*)d_out;

    char* w = (char*)d_ws;
    size_t used = 0;
    auto alloc = [&](size_t bytes) -> char* {
        char* p = w + used;
        used += (bytes + 255) & ~(size_t)255;
        return p;
    };
    unsigned short* Gb = (unsigned short*)alloc((size_t)N * 256 * 2);  // GEMM output (bf16)
    unsigned short* Ab = (unsigned short*)alloc((size_t)N * 256 * 2);  // GEMM input (bf16)
    float* a_src   = (float*)alloc((size_t)N * 4 * 4);
    float* a_dst   = (float*)alloc((size_t)N * 4 * 4);
    float* wts     = (float*)alloc((size_t)Etot * 4 * 4);              // normalized weights
    int* counts    = (int*)alloc((size_t)N * 4);     // doubles as `fill` for scatter
    int* partial   = (int*)alloc((size_t)N * 4);
    int* row_ptr   = (int*)alloc(((size_t)N + 1) * 4);
    int* srcs      = (int*)alloc((size_t)Etot * 4);
    int* blockSums = (int*)alloc(256 * 4);
    unsigned short* Bt = (unsigned short*)alloc((size_t)256 * 256 * 2);

    hipMemsetAsync(counts, 0, (size_t)N * 4, stream);

    hist_kernel<<<(Etot + 255) / 256, 256, 0, stream>>>(dstE, counts, E, N);
    int nScanBlocks = (N + 1023) / 1024;
    scan1_kernel<<<nScanBlocks, 256, 0, stream>>>(counts, partial, blockSums, N);
    scan2_kernel<<<1, 64, 0, stream>>>(blockSums, nScanBlocks);
    finalize_kernel<<<(N + 255) / 256, 256, 0, stream>>>(partial, blockSums, row_ptr, N, Etot);
    hipMemsetAsync(counts, 0, (size_t)N * 4, stream);   // reuse as fill
    scatter_kernel<<<(Etot + 255) / 256, 256, 0, stream>>>(srcE, dstE, row_ptr, counts, srcs, E, N);

    int nodeBlocks = (N + 3) / 4;
    dim3 gg((N + 127) / 128, 2);

    // layer 1
    convertA_kernel<<<(N * 64 + 255) / 256, 256, 0, stream>>>(x, Ab, N);
    transposeW_kernel<<<256, 256, 0, stream>>>(W1, Bt);
    gemm_kernel<<<gg, 256, 0, stream>>>(Ab, Bt, Gb, as1, ad1, a_src, a_dst, N);
    wts_kernel<<<nodeBlocks, 256, 0, stream>>>(a_src, a_dst, row_ptr, srcs, wts, N);
    gather_kernel<<<nodeBlocks, 256, 0, stream>>>(Gb, wts, row_ptr, srcs, b1,
                                                  nullptr, Ab, N);   // relu+bf16 -> layer-2 A

    // layer 2
    transposeW_kernel<<<256, 256, 0, stream>>>(W2, Bt);
    gemm_kernel<<<gg, 256, 0, stream>>>(Ab, Bt, Gb, as2, ad2, a_src, a_dst, N);
    wts_kernel<<<nodeBlocks, 256, 0, stream>>>(a_src, a_dst, row_ptr, srcs, wts, N);
    gather_kernel<<<nodeBlocks, 256, 0, stream>>>(Gb, wts, row_ptr, srcs, b2,
                                                  out, nullptr, N);  // fp32 final
}

// Round 8
// 300.984 us; speedup vs baseline: 1.1094x; 1.1094x over previous
//
#include <hip/hip_runtime.h>
#include <math.h>

#define NEG_SLOPE 0.2f

typedef __attribute__((ext_vector_type(8))) short bf16x8;
typedef __attribute__((ext_vector_type(4))) float f32x4;
typedef __attribute__((ext_vector_type(4))) unsigned short u16x4;
typedef __attribute__((ext_vector_type(8))) unsigned short u16x8;

static __device__ __forceinline__ f32x4 lky4(f32x4 v) {
    f32x4 r;
    r.x = v.x >= 0.f ? v.x : NEG_SLOPE * v.x;
    r.y = v.y >= 0.f ? v.y : NEG_SLOPE * v.y;
    r.z = v.z >= 0.f ? v.z : NEG_SLOPE * v.z;
    r.w = v.w >= 0.f ? v.w : NEG_SLOPE * v.w;
    return r;
}
static __device__ __forceinline__ f32x4 exp4(f32x4 v) {
    f32x4 r;
    r.x = __expf(v.x); r.y = __expf(v.y); r.z = __expf(v.z); r.w = __expf(v.w);
    return r;
}
static __device__ __forceinline__ float bf2f(unsigned short u) {
    return __uint_as_float(((unsigned int)u) << 16);
}
static __device__ __forceinline__ unsigned short f2bf_rne(float f) {
    unsigned int u = __float_as_uint(f);
    u += 0x7fffu + ((u >> 16) & 1u);
    return (unsigned short)(u >> 16);
}

// ---------------- CSR build ----------------

__global__ void hist_kernel(const int* __restrict__ dst, int* __restrict__ counts, int E, int Nn) {
    int i = blockIdx.x * blockDim.x + threadIdx.x;
    int tot = E + Nn;
    if (i < tot) {
        int d = (i < E) ? dst[i] : (i - E);
        atomicAdd(&counts[d], 1);
    }
}

__global__ void scan1_kernel(const int* __restrict__ counts, int* __restrict__ partial,
                             int* __restrict__ blockSums, int Nn) {
    __shared__ int sh[1024];
    int b = blockIdx.x, t = threadIdx.x;
    int base = b * 1024;
    int orig[4];
    for (int r = 0; r < 4; r++) {
        int i = t + r * 256;
        int v = (base + i < Nn) ? counts[base + i] : 0;
        orig[r] = v;
        sh[i] = v;
    }
    __syncthreads();
    for (int off = 1; off < 1024; off <<= 1) {
        int vals[4];
        for (int r = 0; r < 4; r++) { int i = t + r * 256; vals[r] = (i >= off) ? sh[i - off] : 0; }
        __syncthreads();
        for (int r = 0; r < 4; r++) { int i = t + r * 256; sh[i] += vals[r]; }
        __syncthreads();
    }
    for (int r = 0; r < 4; r++) {
        int i = t + r * 256;
        if (base + i < Nn) partial[base + i] = sh[i] - orig[r];
    }
    if (t == 0) blockSums[b] = sh[1023];
}

__global__ void scan2_kernel(int* __restrict__ blockSums, int nb) {
    if (threadIdx.x == 0 && blockIdx.x == 0) {
        int s = 0;
        for (int i = 0; i < nb; i++) { int v = blockSums[i]; blockSums[i] = s; s += v; }
    }
}

__global__ void finalize_kernel(const int* __restrict__ partial, const int* __restrict__ blockOff,
                                int* __restrict__ row_ptr, int Nn, int Etot) {
    int i = blockIdx.x * blockDim.x + threadIdx.x;
    if (i < Nn) row_ptr[i] = partial[i] + blockOff[i >> 10];
    if (i == 0) row_ptr[Nn] = Etot;
}

__global__ void scatter_kernel(const int* __restrict__ srcE, const int* __restrict__ dstE,
                               const int* __restrict__ row_ptr, int* __restrict__ fill,
                               int* __restrict__ srcs, int E, int Nn) {
    int i = blockIdx.x * blockDim.x + threadIdx.x;
    int tot = E + Nn;
    if (i < tot) {
        int s, d;
        if (i < E) { s = srcE[i]; d = dstE[i]; }
        else       { s = d = i - E; }
        int pos = row_ptr[d] + atomicAdd(&fill[d], 1);
        srcs[pos] = s;
    }
}

// ---------------- fp32 -> bf16 RNE ----------------
__global__ void convertA_kernel(const float* __restrict__ X, unsigned short* __restrict__ Ab,
                                int rows) {
    int t = blockIdx.x * 256 + threadIdx.x;
    if (t >= rows * 64) return;
    int r = t >> 6, c4 = t & 63;
    f32x4 v = *((const f32x4*)(X + ((size_t)r << 8)) + c4);
    u16x4 o;
    o.x = f2bf_rne(v.x); o.y = f2bf_rne(v.y);
    o.z = f2bf_rne(v.z); o.w = f2bf_rne(v.w);
    *(u16x4*)(Ab + (size_t)r * 256 + c4 * 4) = o;
}

// W[k][n] fp32 -> Bt[n][k] bf16 RNE  (Bt: [256][256])
__global__ void transposeW_kernel(const float* __restrict__ W, unsigned short* __restrict__ Bt) {
    int t = blockIdx.x * 256 + threadIdx.x;   // 65536 threads
    int n = t >> 8, k = t & 255;
    Bt[(size_t)n * 256 + k] = f2bf_rne(W[k * 256 + n]);
}

// ---------------- bf16 MFMA GEMM, K=256, 2-phase double-buffered ----------------
// Gb[rows,256] (bf16 RNE) = Ab x Bt^T.
__global__ __launch_bounds__(256) void gemm_kernel(const unsigned short* __restrict__ Ab,
                                                   const unsigned short* __restrict__ Bt,
                                                   unsigned short* __restrict__ Gb,
                                                   int rows) {
    __shared__ __align__(128) unsigned char smem[65536];   // 2 x (As 16KB + Bs 16KB)

    int tid = threadIdx.x;
    int lane = tid & 63, wid = tid >> 6;
    int wr = wid >> 1, wc = wid & 1;
    int bm = blockIdx.x * 128;
    int bn = blockIdx.y * 128;

    f32x4 zero4 = {0.f, 0.f, 0.f, 0.f};
    f32x4 acc[4][4];
#pragma unroll
    for (int i = 0; i < 4; i++)
#pragma unroll
        for (int j = 0; j < 4; j++) acc[i][j] = zero4;

    int sr = tid >> 3;   // 0..31
    int sc = tid & 7;    // chunk 0..7

    auto stage = [&](int kt, int buf) {
        unsigned short* As = (unsigned short*)(smem + buf * 32768);
        unsigned short* Bs = As + 8192;
#pragma unroll
        for (int q = 0; q < 4; q++) {
            int rt = q * 32 + sr;
            int gr = bm + rt; if (gr >= rows) gr = rows - 1;
            int cg = sc ^ (rt & 7);
            const unsigned short* gp = Ab + (size_t)gr * 256 + kt + cg * 8;
            unsigned short* lp = As + rt * 64 + sc * 8;
            __builtin_amdgcn_global_load_lds(
                (__attribute__((address_space(1))) void*)(uintptr_t)gp,
                (__attribute__((address_space(3))) void*)lp, 16, 0, 0);
        }
#pragma unroll
        for (int q = 0; q < 4; q++) {
            int rt = q * 32 + sr;
            int gn = bn + rt;
            int cg = sc ^ (rt & 7);
            const unsigned short* gp = Bt + (size_t)gn * 256 + kt + cg * 8;
            unsigned short* lp = Bs + rt * 64 + sc * 8;
            __builtin_amdgcn_global_load_lds(
                (__attribute__((address_space(1))) void*)(uintptr_t)gp,
                (__attribute__((address_space(3))) void*)lp, 16, 0, 0);
        }
    };

    stage(0, 0);
    __syncthreads();

    for (int kt = 0; kt < 4; kt++) {
        if (kt < 3) stage((kt + 1) * 64, (kt + 1) & 1);
        unsigned short* As = (unsigned short*)(smem + (kt & 1) * 32768);
        unsigned short* Bs = As + 8192;
#pragma unroll
        for (int ks = 0; ks < 2; ks++) {
            bf16x8 af[4], bfr[4];
#pragma unroll
            for (int f = 0; f < 4; f++) {
                int r = wr * 64 + f * 16 + (lane & 15);
                int c = (ks * 4 + (lane >> 4)) ^ (r & 7);
                af[f] = *(const bf16x8*)(As + r * 64 + c * 8);
                int rb = wc * 64 + f * 16 + (lane & 15);
                int cb = (ks * 4 + (lane >> 4)) ^ (rb & 7);
                bfr[f] = *(const bf16x8*)(Bs + rb * 64 + cb * 8);
            }
#pragma unroll
            for (int i = 0; i < 4; i++)
#pragma unroll
                for (int j = 0; j < 4; j++)
                    acc[i][j] = __builtin_amdgcn_mfma_f32_16x16x32_bf16(af[i], bfr[j], acc[i][j], 0, 0, 0);
        }
        __syncthreads();
    }

    int r0 = wr * 64 + (lane >> 4) * 4;
    int c0 = wc * 64 + (lane & 15);
#pragma unroll
    for (int i = 0; i < 4; i++) {
#pragma unroll
        for (int j = 0; j < 4; j++) {
#pragma unroll
            for (int rg = 0; rg < 4; rg++) {
                int lr = bm + r0 + i * 16 + rg;
                if (lr < rows) {
                    int col = bn + c0 + j * 16;
                    Gb[(size_t)lr * 256 + col] = f2bf_rne(acc[i][j][rg]);
                }
            }
        }
    }
}

// ---------------- attention coefficients (wave per node, bf16 G) ----------------
__global__ __launch_bounds__(256) void attn_kernel(const unsigned short* __restrict__ Gb,
                                                   const float* __restrict__ att_s,
                                                   const float* __restrict__ att_d,
                                                   float* __restrict__ a_src,
                                                   float* __restrict__ a_dst, int N) {
    int wv = threadIdx.x >> 6, lane = threadIdx.x & 63;
    int n = blockIdx.x * 4 + wv;
    if (n >= N) return;
    u16x4 g4 = *(const u16x4*)(Gb + (size_t)n * 256 + lane * 4);
    f32x4 g;
    g.x = bf2f(g4.x); g.y = bf2f(g4.y); g.z = bf2f(g4.z); g.w = bf2f(g4.w);
    f32x4 s4 = ((const f32x4*)att_s)[lane];
    f32x4 d4 = ((const f32x4*)att_d)[lane];
    f32x4 p = g * s4, q = g * d4;
    float ps = p.x + p.y + p.z + p.w;
    float pd = q.x + q.y + q.z + q.w;
#pragma unroll
    for (int off = 1; off < 16; off <<= 1) {
        ps += __shfl_xor(ps, off);
        pd += __shfl_xor(pd, off);
    }
    if ((lane & 15) == 0) {
        int head = lane >> 4;
        a_src[n * 4 + head] = ps;
        a_dst[n * 4 + head] = pd;
    }
}

// ---------------- fused softmax-weight + gather (wave per node) ----------------
// Staging phase computes unnormalized ev = exp(leaky(a_src[s]+a_dst[n])) per
// staged edge (no max subtraction -- alphas are O(10), softmax shift-invariant)
// and accumulates the per-lane denominator; the inner loop runs on unnormalized
// weights from LDS; one 64-lane reduce + 1/denom scale at the end.
// outF != null -> fp32 (+bias), no relu (final layer)
// outB != null -> relu(h)+bias as bf16 RNE (next layer's GEMM input)
__global__ __launch_bounds__(256) void gather_kernel(const unsigned short* __restrict__ Gb,
                                                     const float* __restrict__ a_src,
                                                     const float* __restrict__ a_dst,
                                                     const int* __restrict__ row_ptr,
                                                     const int* __restrict__ srcs,
                                                     const float* __restrict__ bias,
                                                     float* __restrict__ outF,
                                                     unsigned short* __restrict__ outB,
                                                     int N) {
    __shared__ int s_lds[4][64];
    __shared__ f32x4 w_lds[4][64];
    int wv = threadIdx.x >> 6, lane = threadIdx.x & 63;
    int n = blockIdx.x * 4 + wv;
    if (n >= N) return;
    int half = lane >> 5;   // which edge of a pair
    int sl = lane & 31;     // 16B slice of the 512B row
    int head = sl >> 3;

    int start = row_ptr[n], end = row_ptr[n + 1];
    const f32x4* as4p = (const f32x4*)a_src;
    f32x4 adn4 = *(const f32x4*)(a_dst + (size_t)n * 4);

    float acc[8] = {0.f, 0.f, 0.f, 0.f, 0.f, 0.f, 0.f, 0.f};
    f32x4 dsum4 = {0.f, 0.f, 0.f, 0.f};

    for (int c0 = start; c0 < end; c0 += 64) {
        int cnt = min(64, end - c0);
        if (lane < cnt) {
            int s = srcs[c0 + lane];
            f32x4 ev = exp4(lky4(as4p[s] + adn4));
            s_lds[wv][lane] = s;
            w_lds[wv][lane] = ev;
            dsum4 += ev;
        }
        // wave-private staging; compiler inserts lgkmcnt waits before reads

        int j = 0;
        for (; j + 7 < cnt; j += 8) {
            int e0 = j + half, e1 = j + 2 + half, e2 = j + 4 + half, e3 = j + 6 + half;
            int s0 = s_lds[wv][e0];
            int s1 = s_lds[wv][e1];
            int s2 = s_lds[wv][e2];
            int s3 = s_lds[wv][e3];
            float w0 = ((const float*)&w_lds[wv][e0])[head];
            float w1 = ((const float*)&w_lds[wv][e1])[head];
            float w2 = ((const float*)&w_lds[wv][e2])[head];
            float w3 = ((const float*)&w_lds[wv][e3])[head];
            u16x8 g0 = *(const u16x8*)(Gb + (size_t)s0 * 256 + sl * 8);
            u16x8 g1 = *(const u16x8*)(Gb + (size_t)s1 * 256 + sl * 8);
            u16x8 g2 = *(const u16x8*)(Gb + (size_t)s2 * 256 + sl * 8);
            u16x8 g3 = *(const u16x8*)(Gb + (size_t)s3 * 256 + sl * 8);
#pragma unroll
            for (int k = 0; k < 8; k++) {
                acc[k] = fmaf(bf2f(g0[k]), w0, acc[k]);
                acc[k] = fmaf(bf2f(g1[k]), w1, acc[k]);
                acc[k] = fmaf(bf2f(g2[k]), w2, acc[k]);
                acc[k] = fmaf(bf2f(g3[k]), w3, acc[k]);
            }
        }
        for (; j < cnt; j += 2) {
            int e = j + half;
            if (e < cnt) {
                int s0 = s_lds[wv][e];
                float w0 = ((const float*)&w_lds[wv][e])[head];
                u16x8 g0 = *(const u16x8*)(Gb + (size_t)s0 * 256 + sl * 8);
#pragma unroll
                for (int k = 0; k < 8; k++)
                    acc[k] = fmaf(bf2f(g0[k]), w0, acc[k]);
            }
        }
    }

    // combine halves + denominator reduce
#pragma unroll
    for (int k = 0; k < 8; k++) acc[k] += __shfl_xor(acc[k], 32);
#pragma unroll
    for (int off = 32; off; off >>= 1) {
        dsum4.x += __shfl_xor(dsum4.x, off);
        dsum4.y += __shfl_xor(dsum4.y, off);
        dsum4.z += __shfl_xor(dsum4.z, off);
        dsum4.w += __shfl_xor(dsum4.w, off);
    }
    float den = head == 0 ? dsum4.x : head == 1 ? dsum4.y : head == 2 ? dsum4.z : dsum4.w;
    float rden = 1.0f / den;

    float r[8];
    const float* bp = bias + sl * 8;
#pragma unroll
    for (int k = 0; k < 8; k++) r[k] = acc[k] * rden + bp[k];

    if (outF) {
        if (half == 0) {
            f32x4 v0 = {r[0], r[1], r[2], r[3]};
            f32x4 v1 = {r[4], r[5], r[6], r[7]};
            f32x4* op = (f32x4*)(outF + (size_t)n * 256 + sl * 8);
            op[0] = v0; op[1] = v1;
        }
    } else {
        if (half == 0) {
            u16x8 v;
#pragma unroll
            for (int k = 0; k < 8; k++) v[k] = f2bf_rne(fmaxf(r[k], 0.f));
            *(u16x8*)(outB + (size_t)n * 256 + sl * 8) = v;
        }
    }
}

// ---------------- launch ----------------

extern "C" void kernel_launch(void* const* d_in, const int* in_sizes, int n_in,
                              void* d_out, int out_size, void* d_ws, size_t ws_size,
                              hipStream_t stream) {
    const float* x   = (const float*)d_in[0];
    const int*   ei  = (const int*)d_in[1];
    const float* W1  = (const float*)d_in[2];
    const float* as1 = (const float*)d_in[3];
    const float* ad1 = (const float*)d_in[4];
    const float* b1  = (const float*)d_in[5];
    const float* W2  = (const float*)d_in[6];
    const float* as2 = (const float*)d_in[7];
    const float* ad2 = (const float*)d_in[8];
    const float* b2  = (const float*)d_in[9];

    int N = in_sizes[0] / 256;
    int E = in_sizes[1] / 2;
    int Etot = E + N;
    const int* srcE = ei;
    const int* dstE = ei + E;
    float* out = (float*)d_out;

    char* w = (char*)d_ws;
    size_t used = 0;
    auto alloc = [&](size_t bytes) -> char* {
        char* p = w + used;
        used += (bytes + 255) & ~(size_t)255;
        return p;
    };
    unsigned short* Gb = (unsigned short*)alloc((size_t)N * 256 * 2);  // GEMM output (bf16)
    unsigned short* Ab = (unsigned short*)alloc((size_t)N * 256 * 2);  // GEMM input (bf16)
    float* a_src   = (float*)alloc((size_t)N * 4 * 4);
    float* a_dst   = (float*)alloc((size_t)N * 4 * 4);
    int* counts    = (int*)alloc((size_t)N * 4);     // doubles as `fill` for scatter
    int* partial   = (int*)alloc((size_t)N * 4);
    int* row_ptr   = (int*)alloc(((size_t)N + 1) * 4);
    int* srcs      = (int*)alloc((size_t)Etot * 4);
    int* blockSums = (int*)alloc(256 * 4);
    unsigned short* Bt = (unsigned short*)alloc((size_t)256 * 256 * 2);

    hipMemsetAsync(counts, 0, (size_t)N * 4, stream);

    hist_kernel<<<(Etot + 255) / 256, 256, 0, stream>>>(dstE, counts, E, N);
    int nScanBlocks = (N + 1023) / 1024;
    scan1_kernel<<<nScanBlocks, 256, 0, stream>>>(counts, partial, blockSums, N);
    scan2_kernel<<<1, 64, 0, stream>>>(blockSums, nScanBlocks);
    finalize_kernel<<<(N + 255) / 256, 256, 0, stream>>>(partial, blockSums, row_ptr, N, Etot);
    hipMemsetAsync(counts, 0, (size_t)N * 4, stream);   // reuse as fill
    scatter_kernel<<<(Etot + 255) / 256, 256, 0, stream>>>(srcE, dstE, row_ptr, counts, srcs, E, N);

    int nodeBlocks = (N + 3) / 4;
    dim3 gg((N + 127) / 128, 2);

    // layer 1
    convertA_kernel<<<(N * 64 + 255) / 256, 256, 0, stream>>>(x, Ab, N);
    transposeW_kernel<<<256, 256, 0, stream>>>(W1, Bt);
    gemm_kernel<<<gg, 256, 0, stream>>>(Ab, Bt, Gb, N);
    attn_kernel<<<nodeBlocks, 256, 0, stream>>>(Gb, as1, ad1, a_src, a_dst, N);
    gather_kernel<<<nodeBlocks, 256, 0, stream>>>(Gb, a_src, a_dst, row_ptr, srcs, b1,
                                                  nullptr, Ab, N);   // relu+bf16 -> layer-2 A

    // layer 2
    transposeW_kernel<<<256, 256, 0, stream>>>(W2, Bt);
    gemm_kernel<<<gg, 256, 0, stream>>>(Ab, Bt, Gb, N);
    attn_kernel<<<nodeBlocks, 256, 0, stream>>>(Gb, as2, ad2, a_src, a_dst, N);
    gather_kernel<<<nodeBlocks, 256, 0, stream>>>(Gb, a_src, a_dst, row_ptr, srcs, b2,
                                                  out, nullptr, N);  // fp32 final
}